// Round 16
// baseline (116.557 us; speedup 1.0000x reference)
//
#include <hip/hip_runtime.h>
#include <hip/hip_bf16.h>

#define BATCH 8
#define SEQ 4096
#define EMB 1024
#define HEAD 64
#define N3 192      // 3*HEAD: k | q | v

#define BM 64       // qkv block rows
#define BK 64       // qkv K-step
#define NT (EMB / BK)
#define LSTR 72     // padded LDS row stride in ushorts (64 + 8): 144B = 9*16B

typedef __attribute__((ext_vector_type(4))) float f32x4;
typedef __attribute__((ext_vector_type(8))) short bf16x8;
typedef __attribute__((ext_vector_type(4))) short short4v;
typedef __attribute__((ext_vector_type(4))) float float4v;
typedef __attribute__((ext_vector_type(2))) unsigned int u32x2;

#define LOG2E 1.4426950408889634f
#define QSCALE (0.125f * LOG2E)   // 1/sqrt(64) folded with log2e: scores in log2 domain

// raw v_exp_f32 (exp2): 1 inst vs libm exp2f's ~5
#define FEXP2(x) __builtin_amdgcn_exp2f(x)
// pack two f32 to bf16 pair (truncating) in 1 inst: [b.hi16 | a.hi16]
#define BFPACK(a, b) __builtin_amdgcn_perm(__builtin_bit_cast(unsigned int, (b)), \
                                           __builtin_bit_cast(unsigned int, (a)), 0x07060302u)

static __device__ __forceinline__ unsigned short f2bf(float f) {
  unsigned int x = __builtin_bit_cast(unsigned int, f);
  x += 0x7fffu + ((x >> 16) & 1u);   // RTNE
  return (unsigned short)(x >> 16);
}

// --- Kernel 1: W [1024][192] f32 -> Wt [192][1024] bf16 ---
__global__ __launch_bounds__(256) void wt_kernel(const float* __restrict__ W,
                                                 unsigned short* __restrict__ Wt) {
  int idx = blockIdx.x * 256 + threadIdx.x;
  int k = idx / N3, c = idx % N3;
  Wt[(size_t)c * EMB + k] = f2bf(W[idx]);
}

// --- Kernel 2: canonical LDS-staged GEMM, epilogue packs fragment-linear ---
__global__ __launch_bounds__(256, 2) void qkv_kernel(const float* __restrict__ x,
                                                     const unsigned short* __restrict__ Wt,
                                                     unsigned short* __restrict__ PK,
                                                     unsigned short* __restrict__ PQ,
                                                     unsigned short* __restrict__ PV) {
  __shared__ unsigned short Asm[2][BM][LSTR];    // 2 x 64 x 144B = 18.4 KB
  __shared__ unsigned short Bsm[2][N3][LSTR];    // 2 x 192 x 144B = 55.3 KB

  const int tid = threadIdx.x;
  const int wid = tid >> 6;
  const int lane = tid & 63;
  const int l16 = lane & 15;
  const int lg = lane >> 4;
  const int m0 = blockIdx.x * BM;

  const int ar0 = tid >> 4;        // A row base: +16*i, i<4
  const int ac4 = tid & 15;        // A float4-chunk in row
  const int br0 = tid >> 3;        // B row base: +32*i, i<6
  const int bc = tid & 7;          // B bf16x8-chunk in row

  const float* xa = x + (size_t)(m0 + ar0) * EMB + ac4 * 4;
  const unsigned short* wb = Wt + (size_t)br0 * EMB + bc * 8;

  f32x4 acc[4][3];
#pragma unroll
  for (int mi = 0; mi < 4; ++mi)
#pragma unroll
    for (int ni = 0; ni < 3; ++ni) acc[mi][ni] = (f32x4)0.0f;

  float4v av[4];
  bf16x8 bv[6];

#define ISSUE_LOADS(K0)                                                        \
  {                                                                            \
    _Pragma("unroll") for (int i = 0; i < 4; ++i)                              \
        av[i] = *(const float4v*)(xa + (size_t)(16 * i) * EMB + (K0));         \
    _Pragma("unroll") for (int i = 0; i < 6; ++i)                              \
        bv[i] = *(const bf16x8*)(wb + (size_t)(32 * i) * EMB + (K0));          \
  }

#define WRITE_LDS(BUF)                                                         \
  {                                                                            \
    _Pragma("unroll") for (int i = 0; i < 4; ++i) {                            \
      short4v p;                                                               \
      _Pragma("unroll") for (int j = 0; j < 4; ++j)                            \
          p[j] = (short)f2bf(av[i][j]);                                        \
      *(short4v*)&Asm[BUF][ar0 + 16 * i][ac4 * 4] = p;                         \
    }                                                                          \
    _Pragma("unroll") for (int i = 0; i < 6; ++i)                              \
        *(bf16x8*)&Bsm[BUF][br0 + 32 * i][bc * 8] = bv[i];                     \
  }

#define COMPUTE(BUF)                                                           \
  {                                                                            \
    _Pragma("unroll") for (int kh = 0; kh < 2; ++kh) {                         \
      bf16x8 af[4], bfr[3];                                                    \
      _Pragma("unroll") for (int mi = 0; mi < 4; ++mi)                         \
          af[mi] = *(const bf16x8*)&Asm[BUF][mi * 16 + l16][kh * 32 + lg * 8]; \
      _Pragma("unroll") for (int ni = 0; ni < 3; ++ni)                         \
          bfr[ni] = *(const bf16x8*)&Bsm[BUF][wid * 48 + ni * 16 + l16][kh * 32 + lg * 8]; \
      _Pragma("unroll") for (int mi = 0; mi < 4; ++mi)                         \
        _Pragma("unroll") for (int ni = 0; ni < 3; ++ni)                       \
            acc[mi][ni] = __builtin_amdgcn_mfma_f32_16x16x32_bf16(             \
                af[mi], bfr[ni], acc[mi][ni], 0, 0, 0);                        \
    }                                                                          \
  }

  ISSUE_LOADS(0)
  WRITE_LDS(0)
  __syncthreads();

  int cur = 0;
  for (int t = 0; t < NT; ++t) {
    if (t < NT - 1) ISSUE_LOADS((t + 1) * BK)
    COMPUTE(cur)
    if (t < NT - 1) {
      WRITE_LDS(cur ^ 1)
    }
    __syncthreads();
    cur ^= 1;
  }
#undef ISSUE_LOADS
#undef WRITE_LDS
#undef COMPUTE

  // epilogue: D col = n (l16-resident), row = m0 + mi*16 + lg*4 + r
#pragma unroll
  for (int mi = 0; mi < 4; ++mi) {
#pragma unroll
    for (int ni = 0; ni < 3; ++ni) {
      const int n = wid * 48 + ni * 16 + l16;
#pragma unroll
      for (int r = 0; r < 4; ++r) {
        const int row = m0 + mi * 16 + lg * 4 + r;
        const int bb = row >> 12;
        const int ss = row & (SEQ - 1);
        const float v = acc[mi][ni][r];
        if (n < 64) {            // K
          PK[(((size_t)bb * 256 + (ss >> 4)) * 2 + (n >> 5)) * 512 +
             (ss & 15) * 32 + (n & 31)] = f2bf(v);
        } else if (n < 128) {    // Q (pre-scaled 1/sqrt(64) * log2e)
          const int d = n - 64;
          PQ[(((size_t)bb * 256 + (ss >> 4)) * 2 + (d >> 5)) * 512 +
             (ss & 15) * 32 + (d & 31)] = f2bf(v * QSCALE);
        } else {                 // V
          const int d = n - 128;
          PV[(((size_t)bb * 64 + (ss >> 6)) * 8 + (d >> 4) * 2 + ((ss >> 5) & 1)) * 512 +
             (d & 15) * 32 + (ss & 31)] = f2bf(v);
        }
      }
    }
  }
}

// --- Kernel 3: block-cooperative LDS-staged causal flash attention.
// 512 blocks (batch b = Bid&7 for XCD L2 affinity; 64-q strip u with same-CU
// pairing u / 63-u), 4 waves. Per KV tile the 4 waves DMA the 16KB K+V tile
// into double-buffered LDS via global_load_lds (zero VGPR, drain at barrier,
// hidden under compute), then each wave computes its own 16-q chunk from LDS.
// One tile load feeds 4 chunks. No KV-split, no merge. Online-max softmax.
__global__ __launch_bounds__(256, 4) void attn_kernel(const unsigned short* __restrict__ PK,
                                                      const unsigned short* __restrict__ PQ,
                                                      const unsigned short* __restrict__ PV,
                                                      float* __restrict__ out) {
  __shared__ unsigned short Ksm[2][4096];        // 2 x 8KB K tile (fragment-linear)
  __shared__ unsigned short Vsm[2][4096];        // 2 x 8KB V tile
  __shared__ unsigned short Pl[4][16][LSTR];     // per-wave P^T [q][kv]

  const int tid = threadIdx.x;
  const int wid = tid >> 6;
  const int lane = tid & 63;
  const int l16 = lane & 15;
  const int lg = lane >> 4;
  const int lam = (l16 * 4 + lg) * 8;   // lane's ushort offset in a 1KB sub-tile
  const int wq = wid * 1024;            // wave's staging quarter (ushorts)

  const int Bid = blockIdx.x;
  const int b = Bid & 7;                      // batch -> XCD affinity
  const int idx = Bid >> 3;                   // [0,64)
  const int i_ = idx & 31;
  const int u = (idx >> 5) ? (63 - i_) : i_;  // strip; same-CU blocks: u, 63-u
  const int T = u + 1;                        // KV tiles covering [0, 64u+64)
  const int qc = 4 * u + wid;                 // wave's 16-row chunk
  const int q0c = qc * 16;

  const unsigned short* pkb = PK + (size_t)b * 256 * 1024;
  const unsigned short* pvb = PV + (size_t)b * 64 * 8 * 512;
  const unsigned short* pqb = PQ + (size_t)b * 256 * 1024;

  // Q fragments (B-operand of S^T mfma)
  bf16x8 qf0 = *(const bf16x8*)(pqb + ((size_t)qc * 2 + 0) * 512 + lam);
  bf16x8 qf1 = *(const bf16x8*)(pqb + ((size_t)qc * 2 + 1) * 512 + lam);

  f32x4 o[4];
#pragma unroll
  for (int dd = 0; dd < 4; ++dd) o[dd] = (f32x4)0.0f;
  float m_ = -3.0e38f, lsum = 0.0f;

  // cooperative stage: wave stages its 2KB quarter of K and V tiles (4 DMAs)
#define STAGE(T_, BUF)                                                         \
  {                                                                            \
    const unsigned short* gk = pkb + (size_t)(T_) * 4096 + wq + lane * 8;      \
    const unsigned short* gv = pvb + (size_t)(T_) * 4096 + wq + lane * 8;      \
    __builtin_amdgcn_global_load_lds(                                          \
        (const __attribute__((address_space(1))) void*)gk,                     \
        (__attribute__((address_space(3))) void*)&Ksm[BUF][wq], 16, 0, 0);     \
    __builtin_amdgcn_global_load_lds(                                          \
        (const __attribute__((address_space(1))) void*)(gk + 512),             \
        (__attribute__((address_space(3))) void*)&Ksm[BUF][wq + 512], 16, 0, 0); \
    __builtin_amdgcn_global_load_lds(                                          \
        (const __attribute__((address_space(1))) void*)gv,                     \
        (__attribute__((address_space(3))) void*)&Vsm[BUF][wq], 16, 0, 0);     \
    __builtin_amdgcn_global_load_lds(                                          \
        (const __attribute__((address_space(1))) void*)(gv + 512),             \
        (__attribute__((address_space(3))) void*)&Vsm[BUF][wq + 512], 16, 0, 0); \
  }

  STAGE(0, 0)
  __syncthreads();

  for (int it = 0; it < T; ++it) {
    const int buf = it & 1;
    const int kv0 = it << 6;

    // prefetch next tile into the other buffer (drains at end-of-iter barrier)
    if (it + 1 < T) STAGE(it + 1, buf ^ 1)

    // QK^T from LDS K fragments
    f32x4 s[4];
    __builtin_amdgcn_s_setprio(1);
#pragma unroll
    for (int t = 0; t < 4; ++t) {
      bf16x8 kfa = *(const bf16x8*)&Ksm[buf][(2 * t) * 512 + lam];
      bf16x8 kfb = *(const bf16x8*)&Ksm[buf][(2 * t + 1) * 512 + lam];
      f32x4 z = (f32x4)0.0f;
      z = __builtin_amdgcn_mfma_f32_16x16x32_bf16(kfa, qf0, z, 0, 0, 0);
      s[t] = __builtin_amdgcn_mfma_f32_16x16x32_bf16(kfb, qf1, z, 0, 0, 0);
    }
    __builtin_amdgcn_s_setprio(0);

    // causal mask only on the diagonal tile (uniform branch)
    if (kv0 + 64 > q0c) {
      const int base = kv0 + lg * 4 - q0c - l16;
#pragma unroll
      for (int t = 0; t < 4; ++t)
#pragma unroll
        for (int r = 0; r < 4; ++r)
          if (base + 16 * t + r > 0) s[t][r] = -3.0e38f;
    }

    // online-max softmax (log2 domain)
    {
      float mx = s[0][0];
#pragma unroll
      for (int t = 0; t < 4; ++t)
#pragma unroll
        for (int r = 0; r < 4; ++r) mx = fmaxf(mx, s[t][r]);
      mx = fmaxf(mx, __shfl_xor(mx, 16));
      mx = fmaxf(mx, __shfl_xor(mx, 32));
      if (!__all(mx <= m_)) {
        float mn = fmaxf(m_, mx);
        float al = FEXP2(m_ - mn);
        m_ = mn; lsum *= al;
#pragma unroll
        for (int dd = 0; dd < 4; ++dd) o[dd] *= al;
      }
      float ps = 0.0f;
#pragma unroll
      for (int t = 0; t < 4; ++t) {
        float p0 = FEXP2(s[t][0] - m_);
        float p1 = FEXP2(s[t][1] - m_);
        float p2 = FEXP2(s[t][2] - m_);
        float p3 = FEXP2(s[t][3] - m_);
        ps += (p0 + p1) + (p2 + p3);
        u32x2 w;
        w[0] = BFPACK(p0, p1);
        w[1] = BFPACK(p2, p3);
        *(u32x2*)&Pl[wid][l16][16 * t + lg * 4] = w;   // P^T[q=l16][kv]
      }
      ps += __shfl_xor(ps, 16);
      ps += __shfl_xor(ps, 32);
      lsum += ps;
    }

    // PV from LDS V fragments
    {
      bf16x8 pf0 = *(const bf16x8*)&Pl[wid][l16][lg * 8];
      bf16x8 pf1 = *(const bf16x8*)&Pl[wid][l16][32 + lg * 8];
      __builtin_amdgcn_s_setprio(1);
#pragma unroll
      for (int dd = 0; dd < 4; ++dd) {
        bf16x8 vfa = *(const bf16x8*)&Vsm[buf][(2 * dd) * 512 + lam];
        bf16x8 vfb = *(const bf16x8*)&Vsm[buf][(2 * dd + 1) * 512 + lam];
        o[dd] = __builtin_amdgcn_mfma_f32_16x16x32_bf16(vfa, pf0, o[dd], 0, 0, 0);
        o[dd] = __builtin_amdgcn_mfma_f32_16x16x32_bf16(vfb, pf1, o[dd], 0, 0, 0);
      }
      __builtin_amdgcn_s_setprio(0);
    }

    __syncthreads();   // staged tile ready (vmcnt drain) + buf reads complete
  }
#undef STAGE

  // epilogue: direct per-wave store (no merge). O^T: row d = 16dd+lg*4+r,
  // col q = l16. r spans 4 consecutive d -> float4 store.
  const float inv = 1.0f / lsum;
  float* op = out + ((size_t)b * SEQ + q0c + l16) * HEAD;
#pragma unroll
  for (int dd = 0; dd < 4; ++dd) {
    float4v v;
#pragma unroll
    for (int r = 0; r < 4; ++r) v[r] = o[dd][r] * inv;
    *(float4v*)&op[16 * dd + lg * 4] = v;
  }
}

extern "C" void kernel_launch(void* const* d_in, const int* in_sizes, int n_in,
                              void* d_out, int out_size, void* d_ws, size_t ws_size,
                              hipStream_t stream) {
  (void)in_sizes; (void)n_in; (void)out_size; (void)ws_size;
  const float* x = (const float*)d_in[0];
  const float* W = (const float*)d_in[1];
  float* out = (float*)d_out;

  const size_t MB4 = (size_t)4 * 1024 * 1024;
  unsigned short* Wt = (unsigned short*)d_ws;                               // 384 KB
  unsigned short* PK = (unsigned short*)((char*)d_ws + 512 * 1024);         // 4 MB
  unsigned short* PQ = (unsigned short*)((char*)d_ws + 512 * 1024 + MB4);   // 4 MB
  unsigned short* PV = (unsigned short*)((char*)d_ws + 512 * 1024 + 2 * MB4); // 4 MB

  hipLaunchKernelGGL(wt_kernel, dim3((EMB * N3) / 256), dim3(256), 0, stream, W, Wt);
  hipLaunchKernelGGL(qkv_kernel, dim3((BATCH * SEQ) / BM), dim3(256), 0, stream, x, Wt, PK, PQ, PV);
  hipLaunchKernelGGL(attn_kernel, dim3(BATCH * 64), dim3(256), 0, stream, PK, PQ, PV, out);
}